// Round 10
// baseline (222.458 us; speedup 1.0000x reference)
//
#include <hip/hip_runtime.h>
#include <stdint.h>

typedef __attribute__((ext_vector_type(4))) float f32x4;
typedef __attribute__((ext_vector_type(16))) float f32x16;
typedef __attribute__((ext_vector_type(8))) short short8;
typedef unsigned short u16;

#define NH 16
#define HD 64
#define SEQ 4096
#define BATCH 4
#define NROWS (BATCH * SEQ)      // 16384
#define DIMC 1024
#define QKVC 3072
#define SCALE 0.125f

__device__ __forceinline__ u16 f2bf(float f) {
  union { float f; uint32_t u; } v; v.f = f;
  uint32_t u = v.u;
  uint32_t r = (u + 0x7fffu + ((u >> 16) & 1u)) >> 16;
  return (u16)r;
}
__device__ __forceinline__ float bf2f(u16 h) {
  union { uint32_t u; float f; } v; v.u = ((uint32_t)h) << 16;
  return v.f;
}

// ---------------- fp32 -> bf16 elementwise convert (vectorized) ----------------
__global__ __launch_bounds__(256) void cvt_kernel(const float* __restrict__ in,
                                                  u16* __restrict__ out, int n4) {
  int i = blockIdx.x * 256 + threadIdx.x;
  if (i >= n4) return;
  float4 v = ((const float4*)in)[i];
  ushort4 o;
  o.x = f2bf(v.x); o.y = f2bf(v.y); o.z = f2bf(v.z); o.w = f2bf(v.w);
  ((ushort4*)out)[i] = o;
}

// ---------------- fp32 [R][C] -> bf16 [C][R] transpose ----------------
__global__ __launch_bounds__(256) void transpose_cvt(const float* __restrict__ in,
                                                     u16* __restrict__ out, int R, int C) {
  __shared__ float t[32][33];
  int nbx = C >> 5;
  int bx = blockIdx.x % nbx, by = blockIdx.x / nbx;
  int r0 = by << 5, c0 = bx << 5;
  int tid = threadIdx.x;
#pragma unroll
  for (int i = 0; i < 4; i++) {
    int id = i * 256 + tid; int lr = id >> 5, lc = id & 31;
    t[lr][lc] = in[(size_t)(r0 + lr) * C + (c0 + lc)];
  }
  __syncthreads();
#pragma unroll
  for (int i = 0; i < 4; i++) {
    int id = i * 256 + tid; int lr = id >> 5, lc = id & 31;
    out[(size_t)(c0 + lr) * R + (r0 + lc)] = f2bf(t[lc][lr]);
  }
}

// ---------------- bf16 GEMM: C[M,N] = A[M,K] * Bt[N,K]^T ----------------
// Round-6 schedule (best measured) + 32x32x16 MFMA (-17% matrix-pipe cycles,
// half the MFMA instructions) + fully hoisted LDS read bases (base+imm only).
// BM=BN=256, BK=64, 512 thr = 8 waves (2M x 4N), per-wave 128x64:
//   acc = f32x16[4][2] (128 regs). Frags: a[4 mt][4 ks], b[2 nt][4 ks].
// A/B frag layout (32x32x16): row|col = lane&31, k = (lane>>5)*8 + e.
// C/D: col = lane&31, row = (r&3) + 8*(r>>2) + 4*(lane>>5)  [m74/m101].
// LDS flat [A0|A1|B0|B1] 16384 u16 each; chunk-XOR swizzle c^(row&7) realized
// by pre-swizzled global source (stores) and 8 per-ks hoisted bases (reads).
template <int OUT_BF16, int DO_SUMS>
__global__ __launch_bounds__(512, 1) void gemm_bt(const u16* __restrict__ A,
                                                  const u16* __restrict__ Bt,
                                                  void* __restrict__ Cv,
                                                  float* __restrict__ chk,
                                                  float* __restrict__ chv,
                                                  int M, int N, int K) {
  __shared__ __align__(16) u16 lds[65536];  // A0|A1|B0|B1, 16384 u16 each
  int nbx = N >> 8;
  int nwg = gridDim.x;
  int bid = blockIdx.x;
  int cpx = nwg >> 3;                       // grids are multiples of 8
  int swz = (bid & 7) * cpx + (bid >> 3);
  int bx = swz % nbx, by = swz / nbx;
  int tid = threadIdx.x, lane = tid & 63, wv = tid >> 6;
  int wr = wv >> 2, wc = wv & 3;            // wave grid 2 (M) x 4 (N)
  int l31 = lane & 31, hg = lane >> 5;
  int rx = lane & 7;                        // (row&7) for all frag reads
  int rsub = lane >> 3;                     // staging: row within 8-row unit
  int clog = (lane & 7) ^ rsub;             // staging: logical (global) chunk

  const u16* Ap = A + (size_t)(by * 256) * K;
  const u16* Bp = Bt + (size_t)(bx * 256) * K;

  // 8 hoisted LDS read bases: per-kstep chunk swizzle folded in.
  const u16* aB[4];
  const u16* bB[4];
#pragma unroll
  for (int ks = 0; ks < 4; ks++) {
    int ck = (((ks << 1) | hg) ^ rx) << 3;
    aB[ks] = lds + (wr * 128 + l31) * 64 + ck;
    bB[ks] = lds + 32768 + (wc * 64 + l31) * 64 + ck;
  }

  f32x16 acc[4][2];
#pragma unroll
  for (int m = 0; m < 4; m++)
#pragma unroll
    for (int n = 0; n < 2; n++)
#pragma unroll
      for (int r = 0; r < 16; r++) acc[m][n][r] = 0.f;

  short8 af[4][4];  // [mt][ks]
  short8 bf[2][4];  // [nt][ks]

#define ISSUE_A(HALF, L, T, DBUF) do {                                          \
    int ru_ = (HALF) * 128 + (L) * 64 + wv * 8;                                 \
    const u16* g_ = Ap + (size_t)(ru_ + rsub) * K + (T) * 64 + clog * 8;        \
    __builtin_amdgcn_global_load_lds(                                           \
        (const __attribute__((address_space(1))) uint32_t*)g_,                  \
        (__attribute__((address_space(3)))                                      \
             uint32_t*)&lds[(DBUF) * 16384 + ru_ * 64],                         \
        16, 0, 0);                                                              \
  } while (0)

#define ISSUE_B(HALF, L, T, DBUF) do {                                          \
    int ru_ = (HALF) * 128 + (L) * 64 + wv * 8;                                 \
    const u16* g_ = Bp + (size_t)(ru_ + rsub) * K + (T) * 64 + clog * 8;        \
    __builtin_amdgcn_global_load_lds(                                           \
        (const __attribute__((address_space(1))) uint32_t*)g_,                  \
        (__attribute__((address_space(3)))                                      \
             uint32_t*)&lds[32768 + (DBUF) * 16384 + ru_ * 64],                 \
        16, 0, 0);                                                              \
  } while (0)

  // reads: pure base+imm (u16 units; bytes < 64KB imm range)
#define LDA1(MT, KS, BUF) \
    af[MT][KS] = *(const short8*)(aB[KS] + (BUF) * 16384 + (MT) * 2048)
#define LDB1(NT, KS, BUF) \
    bf[NT][KS] = *(const short8*)(bB[KS] + (BUF) * 16384 + (NT) * 2048)

#define READ_KS(KS, BUF)                                                        \
    LDA1(0, KS, BUF); LDA1(1, KS, BUF); LDA1(2, KS, BUF); LDA1(3, KS, BUF);     \
    LDB1(0, KS, BUF); LDB1(1, KS, BUF)

#define MFMA_KS(KS) do {                                                        \
    _Pragma("unroll")                                                           \
    for (int mt = 0; mt < 4; mt++)                                              \
      _Pragma("unroll")                                                         \
      for (int nt = 0; nt < 2; nt++)                                            \
        acc[mt][nt] = __builtin_amdgcn_mfma_f32_32x32x16_bf16(                  \
            af[mt][KS], bf[nt][KS], acc[mt][nt], 0, 0, 0);                      \
  } while (0)

  int NT = K >> 6;
  // prologue: stage tile 0 into buf0, drain
  ISSUE_A(0, 0, 0, 0); ISSUE_A(0, 1, 0, 0); ISSUE_A(1, 0, 0, 0); ISSUE_A(1, 1, 0, 0);
  ISSUE_B(0, 0, 0, 0); ISSUE_B(0, 1, 0, 0); ISSUE_B(1, 0, 0, 0); ISSUE_B(1, 1, 0, 0);
  __syncthreads();

  for (int t = 0; t < NT; t++) {
    int buf = t & 1;
    // reads ks0,ks1 (12)
    READ_KS(0, buf);
    READ_KS(1, buf);
    __builtin_amdgcn_sched_barrier(0);
    // stage A(t+1) into other buffer
    if (t + 1 < NT) {
      ISSUE_A(0, 0, t + 1, buf ^ 1); ISSUE_A(0, 1, t + 1, buf ^ 1);
      ISSUE_A(1, 0, t + 1, buf ^ 1); ISSUE_A(1, 1, t + 1, buf ^ 1);
    }
    __builtin_amdgcn_sched_barrier(0);
    // reads ks2,ks3 (12)
    READ_KS(2, buf);
    READ_KS(3, buf);
    __builtin_amdgcn_sched_barrier(0);
    // stage B(t+1)
    if (t + 1 < NT) {
      ISSUE_B(0, 0, t + 1, buf ^ 1); ISSUE_B(0, 1, t + 1, buf ^ 1);
      ISSUE_B(1, 0, t + 1, buf ^ 1); ISSUE_B(1, 1, t + 1, buf ^ 1);
    }
    __builtin_amdgcn_sched_barrier(0);
    // MFMA staircase: compiler-counted lgkm waits per ks-cluster
    __builtin_amdgcn_s_setprio(1);
    MFMA_KS(0);
    __builtin_amdgcn_sched_barrier(0);
    MFMA_KS(1);
    __builtin_amdgcn_sched_barrier(0);
    MFMA_KS(2);
    __builtin_amdgcn_sched_barrier(0);
    MFMA_KS(3);
    __builtin_amdgcn_s_setprio(0);
    __syncthreads();   // drains stages (vmcnt) + lgkm; one barrier per tile
  }

#undef ISSUE_A
#undef ISSUE_B
#undef LDA1
#undef LDB1
#undef READ_KS
#undef MFMA_KS

  int rb = by * 256 + wr * 128, cb = bx * 256 + wc * 64;

  if (DO_SUMS && cb >= 1024) {
    // fused chunk means: chunk = 64 rows = mt pair; col owned by lanes l,l+32.
#pragma unroll
    for (int pair = 0; pair < 2; pair++)
#pragma unroll
      for (int nt = 0; nt < 2; nt++) {
        float s = 0.f;
#pragma unroll
        for (int mi = 0; mi < 2; mi++)
#pragma unroll
          for (int r = 0; r < 16; r++) s += acc[pair * 2 + mi][nt][r];
        s += __shfl_xor(s, 32);
        if (hg == 0) {
          int grb = rb + pair * 64;
          int b = grb >> 12, c = (grb >> 6) & 63;
          int cg = cb + nt * 32 + l31;
          int col = cg & 1023;
          int h = col >> 6, d = col & 63;
          float* dst = (cg < 2048) ? chk : chv;
          dst[(((size_t)(b * 16 + h)) * 64 + c) * 64 + d] = s * 0.015625f;
        }
      }
  }

#pragma unroll
  for (int mt = 0; mt < 4; mt++)
#pragma unroll
    for (int nt = 0; nt < 2; nt++)
#pragma unroll
      for (int r = 0; r < 16; r++) {
        int rg = rb + mt * 32 + (r & 3) + 8 * (r >> 2) + 4 * hg;
        int cg = cb + nt * 32 + l31;
        float v = acc[mt][nt][r];
        if (OUT_BF16)
          ((u16*)Cv)[(size_t)rg * N + cg] = f2bf(v);
        else
          ((float*)Cv)[(size_t)rg * N + cg] = v;
      }
}

// ---------------- exclusive cumsum over chunks (4-way split scan) ----------
__global__ __launch_bounds__(256) void cumsum_excl(const float* __restrict__ ck,
                                                   const float* __restrict__ cv,
                                                   float* __restrict__ cuk,
                                                   float* __restrict__ cuv) {
  __shared__ float qk[4][64], qv[4][64];
  int bh = blockIdx.x;                       // 64 blocks (b*16+h)
  int d = threadIdx.x & 63, q = threadIdx.x >> 6;
  size_t base = ((size_t)bh * 64) * 64 + d;
  float sk = 0.f, sv = 0.f;
  for (int c = q * 16; c < q * 16 + 16; c++) {
    sk += ck[base + (size_t)c * 64];
    sv += cv[base + (size_t)c * 64];
  }
  qk[q][d] = sk; qv[q][d] = sv;
  __syncthreads();
  float ak = 0.f, av = 0.f;
  for (int p = 0; p < q; p++) { ak += qk[p][d]; av += qv[p][d]; }
  for (int c = q * 16; c < q * 16 + 16; c++) {
    size_t i = base + (size_t)c * 64;
    cuk[i] = ak; cuv[i] = av;
    ak += ck[i]; av += cv[i];
  }
}

// ---------------- per-chunk attention + cross term ----------------
__global__ __launch_bounds__(256) void attn_kernel(const u16* __restrict__ qkv,
                                                   const float* __restrict__ cuk,
                                                   const float* __restrict__ cuv,
                                                   u16* __restrict__ out) {
  int blk = blockIdx.x;
  int c = blk & 63, h = (blk >> 6) & 15, b = blk >> 10;
  int row0 = b * SEQ + c * 64;
  __shared__ u16 q_s[64][80];
  __shared__ u16 k_s[64][80];
  __shared__ u16 vt_s[64][80];   // V transposed: vt_s[d][krow]
  __shared__ u16 p_s[64][80];
  __shared__ u16 ck_s[64];
  __shared__ float cv_s[64];
  int tid = threadIdx.x;
  {
    int r = tid >> 2, qt = tid & 3;
    const u16* rp = qkv + (size_t)(row0 + r) * QKVC + h * 64 + qt * 16;
    uint4 q0 = *(const uint4*)rp;          uint4 q1 = *(const uint4*)(rp + 8);
    uint4 k0 = *(const uint4*)(rp + 1024); uint4 k1 = *(const uint4*)(rp + 1032);
    uint4 v0 = *(const uint4*)(rp + 2048); uint4 v1 = *(const uint4*)(rp + 2056);
    *(uint4*)&q_s[r][qt * 16] = q0;     *(uint4*)&q_s[r][qt * 16 + 8] = q1;
    *(uint4*)&k_s[r][qt * 16] = k0;     *(uint4*)&k_s[r][qt * 16 + 8] = k1;
    const u16* vv0 = (const u16*)&v0;   const u16* vv1 = (const u16*)&v1;
#pragma unroll
    for (int j = 0; j < 8; j++) vt_s[qt * 16 + j][r] = vv0[j];
#pragma unroll
    for (int j = 0; j < 8; j++) vt_s[qt * 16 + 8 + j][r] = vv1[j];
    if (tid < 64) {
      ck_s[tid] = f2bf(cuk[(size_t)blk * 64 + tid]);
      cv_s[tid] = cuv[(size_t)blk * 64 + tid];
    }
  }
  __syncthreads();

  int lane = tid & 63, w = tid >> 6;
  int lr = lane & 15, g = lane >> 4;
  f32x4 accS[4];
#pragma unroll
  for (int n = 0; n < 4; n++) accS[n] = (f32x4){0.f, 0.f, 0.f, 0.f};
  f32x4 accC = (f32x4){0.f, 0.f, 0.f, 0.f};
  short8 zf = (short8){0, 0, 0, 0, 0, 0, 0, 0};
#pragma unroll
  for (int kt = 0; kt < 2; kt++) {
    int lk = kt * 32 + g * 8;
    short8 af = *(const short8*)&q_s[w * 16 + lr][lk];
    short8 cf = (lr == 0) ? *(const short8*)&ck_s[lk] : zf;
    accC = __builtin_amdgcn_mfma_f32_16x16x32_bf16(af, cf, accC, 0, 0, 0);
#pragma unroll
    for (int n = 0; n < 4; n++) {
      short8 bf = *(const short8*)&k_s[n * 16 + lr][lk];
      accS[n] = __builtin_amdgcn_mfma_f32_16x16x32_bf16(af, bf, accS[n], 0, 0, 0);
    }
  }
  float crossv[4];
#pragma unroll
  for (int r4 = 0; r4 < 4; r4++) {
    int row = w * 16 + g * 4 + r4;
    float x[4];
    float mx = -3.4e38f;
#pragma unroll
    for (int n = 0; n < 4; n++) {
      int col = n * 16 + lr;
      x[n] = ((col & 63) > (row & 63)) ? -65000.0f : accS[n][r4] * SCALE;
      mx = fmaxf(mx, x[n]);
    }
    mx = fmaxf(mx, __shfl_xor(mx, 1));
    mx = fmaxf(mx, __shfl_xor(mx, 2));
    mx = fmaxf(mx, __shfl_xor(mx, 4));
    mx = fmaxf(mx, __shfl_xor(mx, 8));
    float p[4], sum = 0.f;
#pragma unroll
    for (int n = 0; n < 4; n++) { p[n] = __expf(x[n] - mx); sum += p[n]; }
    sum += __shfl_xor(sum, 1);
    sum += __shfl_xor(sum, 2);
    sum += __shfl_xor(sum, 4);
    sum += __shfl_xor(sum, 8);
    float inv = 1.0f / sum;
#pragma unroll
    for (int n = 0; n < 4; n++) p_s[row][n * 16 + lr] = f2bf(p[n] * inv);
    float sg = 1.0f / (1.0f + __expf(-accC[r4] * SCALE));
    crossv[r4] = __shfl(sg, (lane & 48));
  }
  __syncthreads();
  f32x4 accO[4];
#pragma unroll
  for (int n = 0; n < 4; n++) accO[n] = (f32x4){0.f, 0.f, 0.f, 0.f};
#pragma unroll
  for (int kt = 0; kt < 2; kt++) {
    int lk = kt * 32 + g * 8;
    short8 pf = *(const short8*)&p_s[w * 16 + lr][lk];
#pragma unroll
    for (int n = 0; n < 4; n++) {
      short8 vf = *(const short8*)&vt_s[n * 16 + lr][lk];
      accO[n] = __builtin_amdgcn_mfma_f32_16x16x32_bf16(pf, vf, accO[n], 0, 0, 0);
    }
  }
#pragma unroll
  for (int n = 0; n < 4; n++)
#pragma unroll
    for (int r4 = 0; r4 < 4; r4++) {
      int row = w * 16 + g * 4 + r4;
      int col = n * 16 + lr;
      float v = accO[n][r4] + crossv[r4] * cv_s[col] * 0.5f;
      out[(size_t)(row0 + row) * DIMC + h * 64 + col] = f2bf(v);
    }
}

extern "C" void kernel_launch(void* const* d_in, const int* in_sizes, int n_in,
                              void* d_out, int out_size, void* d_ws, size_t ws_size,
                              hipStream_t stream) {
  const float* x = (const float*)d_in[0];
  const float* Wqkv = (const float*)d_in[1];
  const float* Wout = (const float*)d_in[2];
  char* ws = (char*)d_ws;
  size_t off = 0;
  auto alloc = [&](size_t b) {
    void* p = ws + off;
    off += (b + 255) & ~(size_t)255;
    return p;
  };
  u16* xb = (u16*)alloc((size_t)NROWS * DIMC * 2);        // 32MB, reused as attnb
  u16* wqt = (u16*)alloc((size_t)QKVC * DIMC * 2);        // 6MB
  u16* wot = (u16*)alloc((size_t)DIMC * DIMC * 2);        // 2MB
  u16* qkvb = (u16*)alloc((size_t)NROWS * QKVC * 2);      // 96MB
  float* chk = (float*)alloc((size_t)4096 * 64 * 4);
  float* chv = (float*)alloc((size_t)4096 * 64 * 4);
  float* cuk = (float*)alloc((size_t)4096 * 64 * 4);
  float* cuv = (float*)alloc((size_t)4096 * 64 * 4);
  u16* attnb = xb;

  cvt_kernel<<<16384, 256, 0, stream>>>(x, xb, NROWS * DIMC / 4);
  transpose_cvt<<<3072, 256, 0, stream>>>(Wqkv, wqt, DIMC, QKVC);
  transpose_cvt<<<1024, 256, 0, stream>>>(Wout, wot, DIMC, DIMC);
  gemm_bt<1, 1><<<768, 512, 0, stream>>>(xb, wqt, qkvb, chk, chv, NROWS, QKVC, DIMC);
  cumsum_excl<<<64, 256, 0, stream>>>(chk, chv, cuk, cuv);
  attn_kernel<<<4096, 256, 0, stream>>>(qkvb, cuk, cuv, attnb);
  gemm_bt<0, 0><<<256, 512, 0, stream>>>(attnb, wot, d_out, nullptr, nullptr,
                                         NROWS, DIMC, DIMC);
}

// Round 11
// 200.597 us; speedup vs baseline: 1.1090x; 1.1090x over previous
//
#include <hip/hip_runtime.h>
#include <stdint.h>

typedef __attribute__((ext_vector_type(4))) float f32x4;
typedef __attribute__((ext_vector_type(8))) short short8;
typedef unsigned short u16;

#define NH 16
#define HD 64
#define SEQ 4096
#define BATCH 4
#define NROWS (BATCH * SEQ)      // 16384
#define DIMC 1024
#define QKVC 3072
#define SCALE 0.125f

__device__ __forceinline__ u16 f2bf(float f) {
  union { float f; uint32_t u; } v; v.f = f;
  uint32_t u = v.u;
  uint32_t r = (u + 0x7fffu + ((u >> 16) & 1u)) >> 16;
  return (u16)r;
}
__device__ __forceinline__ float bf2f(u16 h) {
  union { uint32_t u; float f; } v; v.u = ((uint32_t)h) << 16;
  return v.f;
}

// ---------------- fp32 -> bf16 elementwise convert (vectorized) ----------------
__global__ __launch_bounds__(256) void cvt_kernel(const float* __restrict__ in,
                                                  u16* __restrict__ out, int n4) {
  int i = blockIdx.x * 256 + threadIdx.x;
  if (i >= n4) return;
  float4 v = ((const float4*)in)[i];
  ushort4 o;
  o.x = f2bf(v.x); o.y = f2bf(v.y); o.z = f2bf(v.z); o.w = f2bf(v.w);
  ((ushort4*)out)[i] = o;
}

// ---------------- fp32 [R][C] -> bf16 [C][R] transpose ----------------
__global__ __launch_bounds__(256) void transpose_cvt(const float* __restrict__ in,
                                                     u16* __restrict__ out, int R, int C) {
  __shared__ float t[32][33];
  int nbx = C >> 5;
  int bx = blockIdx.x % nbx, by = blockIdx.x / nbx;
  int r0 = by << 5, c0 = bx << 5;
  int tid = threadIdx.x;
#pragma unroll
  for (int i = 0; i < 4; i++) {
    int id = i * 256 + tid; int lr = id >> 5, lc = id & 31;
    t[lr][lc] = in[(size_t)(r0 + lr) * C + (c0 + lc)];
  }
  __syncthreads();
#pragma unroll
  for (int i = 0; i < 4; i++) {
    int id = i * 256 + tid; int lr = id >> 5, lc = id & 31;
    out[(size_t)(c0 + lr) * R + (r0 + lc)] = f2bf(t[lc][lr]);
  }
}

// ---------------- bf16 GEMM: C[M,N] = A[M,K] * Bt[N,K]^T ----------------
// Round-6 structure (best measured: 107us, MfmaUtil 41-43%, 0 conflicts,
// no spill). BM=BN=256, BK=64, 512 thr = 8 waves (2M x 4N), per-wave 128x64
// (acc[8][4], 16x16x32 MFMA). LDS 128 KiB = 2 dbuf x (A 256x64 + B 256x64).
// One barrier per K-tile; reads grouped ahead of MFMA staircase; compiler
// inserts counted lgkm waits so tail reads drain under MFMA.
template <int OUT_BF16, int DO_SUMS>
__global__ __launch_bounds__(512, 2) void gemm_bt(const u16* __restrict__ A,
                                                  const u16* __restrict__ Bt,
                                                  void* __restrict__ Cv,
                                                  float* __restrict__ chk,
                                                  float* __restrict__ chv,
                                                  int M, int N, int K) {
  __shared__ __align__(16) u16 lds2[2][32768];   // per dbuf: A[0..16383], B[16384..32767]
  int nbx = N >> 8;
  int nwg = gridDim.x;
  int bid = blockIdx.x;
  int cpx = nwg >> 3;                       // grids are multiples of 8
  int swz = (bid & 7) * cpx + (bid >> 3);
  int bx = swz % nbx, by = swz / nbx;
  int tid = threadIdx.x, lane = tid & 63, wv = tid >> 6;
  int wr = wv >> 2, wc = wv & 3;            // wave grid 2 (M) x 4 (N)
  int lr = lane & 15, g = lane >> 4;
  int rx = lr & 7;
  int rsub = lane >> 3;                     // staging: row within 8-row unit
  int clog = (lane & 7) ^ rsub;             // staging: logical (global) chunk

  const u16* Ap = A + (size_t)(by * 256) * K;
  const u16* Bp = Bt + (size_t)(bx * 256) * K;

  f32x4 acc[8][4];
#pragma unroll
  for (int m = 0; m < 8; m++)
#pragma unroll
    for (int n = 0; n < 4; n++) acc[m][n] = (f32x4){0.f, 0.f, 0.f, 0.f};

  short8 a0[4][2], a1[4][2], b0[2][2], b1[2][2];

#define ISSUE_A(HALF, L, T) do {                                                \
    int ru_ = (HALF) * 128 + (L) * 64 + wv * 8;                                 \
    const u16* g_ = Ap + (size_t)(ru_ + rsub) * K + (T) * 64 + clog * 8;        \
    __builtin_amdgcn_global_load_lds(                                           \
        (const __attribute__((address_space(1))) uint32_t*)g_,                  \
        (__attribute__((address_space(3))) uint32_t*)&lds2[(T) & 1][ru_ * 64],  \
        16, 0, 0);                                                              \
  } while (0)

#define ISSUE_B(HALF, L, T) do {                                                \
    int ru_ = (HALF) * 128 + (L) * 64 + wv * 8;                                 \
    const u16* g_ = Bp + (size_t)(ru_ + rsub) * K + (T) * 64 + clog * 8;        \
    __builtin_amdgcn_global_load_lds(                                           \
        (const __attribute__((address_space(1))) uint32_t*)g_,                  \
        (__attribute__((address_space(3)))                                      \
             uint32_t*)&lds2[(T) & 1][16384 + ru_ * 64],                        \
        16, 0, 0);                                                              \
  } while (0)

#define LDA(DST, MH, T) do {                                                    \
    _Pragma("unroll")                                                           \
    for (int m2 = 0; m2 < 2; m2++) {                                            \
      int row_ = wr * 128 + ((MH) * 2 + m2) * 16 + lr;                          \
      const u16* bp_ = &lds2[(T) & 1][row_ * 64];                               \
      _Pragma("unroll")                                                         \
      for (int s = 0; s < 2; s++)                                               \
        DST[m2][s] = *(const short8*)(bp_ + (((s * 4 + g) ^ rx) << 3));         \
    }                                                                           \
  } while (0)

#define LDA4(DST, MH, T) do {                                                   \
    _Pragma("unroll")                                                           \
    for (int m2 = 0; m2 < 4; m2++) {                                            \
      int row_ = wr * 128 + ((MH) * 4 + m2) * 16 + lr;                          \
      const u16* bp_ = &lds2[(T) & 1][row_ * 64];                               \
      _Pragma("unroll")                                                         \
      for (int s = 0; s < 2; s++)                                               \
        DST[m2][s] = *(const short8*)(bp_ + (((s * 4 + g) ^ rx) << 3));         \
    }                                                                           \
  } while (0)

#define LDB(DST, NHh, T) do {                                                   \
    _Pragma("unroll")                                                           \
    for (int n2 = 0; n2 < 2; n2++) {                                            \
      int row_ = wc * 64 + ((NHh) * 2 + n2) * 16 + lr;                          \
      const u16* bp_ = &lds2[(T) & 1][16384 + row_ * 64];                       \
      _Pragma("unroll")                                                         \
      for (int s = 0; s < 2; s++)                                               \
        DST[n2][s] = *(const short8*)(bp_ + (((s * 4 + g) ^ rx) << 3));         \
    }                                                                           \
  } while (0)

#define MFMA_Q(MH, NHh, AA, BB) do {                                            \
    _Pragma("unroll")                                                           \
    for (int s = 0; s < 2; s++)                                                 \
      _Pragma("unroll")                                                         \
      for (int m2 = 0; m2 < 4; m2++)                                            \
        _Pragma("unroll")                                                       \
        for (int n2 = 0; n2 < 2; n2++)                                          \
          acc[(MH) * 4 + m2][(NHh) * 2 + n2] =                                  \
              __builtin_amdgcn_mfma_f32_16x16x32_bf16(                          \
                  AA[m2][s], BB[n2][s], acc[(MH) * 4 + m2][(NHh) * 2 + n2],     \
                  0, 0, 0);                                                     \
  } while (0)

  int NT = K >> 6;
  // prologue: stage tile 0 into buf0, drain
  ISSUE_A(0, 0, 0); ISSUE_A(0, 1, 0); ISSUE_A(1, 0, 0); ISSUE_A(1, 1, 0);
  ISSUE_B(0, 0, 0); ISSUE_B(0, 1, 0); ISSUE_B(1, 0, 0); ISSUE_B(1, 1, 0);
  __syncthreads();

  for (int t = 0; t < NT; t++) {
    // group 1: frags for Q00
    LDA4(a0, 0, t);
    LDB(b0, 0, t);
    __builtin_amdgcn_sched_barrier(0);
    // stage A of tile t+1 (other buffer; prior readers retired at last barrier)
    if (t + 1 < NT) {
      ISSUE_A(0, 0, t + 1); ISSUE_A(0, 1, t + 1);
      ISSUE_A(1, 0, t + 1); ISSUE_A(1, 1, t + 1);
    }
    __builtin_amdgcn_sched_barrier(0);
    // group 2: remaining frags
    LDB(b1, 1, t);
    LDA4(a1, 1, t);
    __builtin_amdgcn_sched_barrier(0);
    // stage B of tile t+1
    if (t + 1 < NT) {
      ISSUE_B(0, 0, t + 1); ISSUE_B(0, 1, t + 1);
      ISSUE_B(1, 0, t + 1); ISSUE_B(1, 1, t + 1);
    }
    __builtin_amdgcn_sched_barrier(0);
    // MFMA staircase: compiler-counted lgkm waits
    __builtin_amdgcn_s_setprio(1);
    MFMA_Q(0, 0, a0, b0);
    __builtin_amdgcn_sched_barrier(0);
    MFMA_Q(0, 1, a0, b1);
    __builtin_amdgcn_sched_barrier(0);
    MFMA_Q(1, 1, a1, b1);
    __builtin_amdgcn_sched_barrier(0);
    MFMA_Q(1, 0, a1, b0);
    __builtin_amdgcn_s_setprio(0);
    __syncthreads();   // drains own vmcnt (stages) + lgkm; one barrier per tile
  }

#undef ISSUE_A
#undef ISSUE_B
#undef LDA
#undef LDA4
#undef LDB
#undef MFMA_Q

  int rb = by * 256 + wr * 128, cb = bx * 256 + wc * 64;

  if (DO_SUMS && cb >= 1024) {
    // fused chunk means: wave owns chunks (wr*2+mh); sum fp32 acc over rows.
#pragma unroll
    for (int mh = 0; mh < 2; mh++)
#pragma unroll
      for (int n = 0; n < 4; n++) {
        float sum = 0.f;
#pragma unroll
        for (int m = mh * 4; m < mh * 4 + 4; m++)
#pragma unroll
          for (int r = 0; r < 4; r++) sum += acc[m][n][r];
        sum += __shfl_xor(sum, 16);
        sum += __shfl_xor(sum, 32);
        if (g == 0) {
          int grb = rb + mh * 64;
          int b = grb >> 12, c = (grb >> 6) & 63;
          int cg = cb + n * 16 + lr;
          int col = cg & 1023;
          int h = col >> 6, d = col & 63;
          float* dst = (cg < 2048) ? chk : chv;
          dst[(((size_t)(b * 16 + h)) * 64 + c) * 64 + d] = sum * 0.015625f;
        }
      }
  }

#pragma unroll
  for (int m = 0; m < 8; m++)
#pragma unroll
    for (int n = 0; n < 4; n++)
#pragma unroll
      for (int r = 0; r < 4; r++) {
        int rg = rb + m * 16 + g * 4 + r;
        int cg = cb + n * 16 + lr;
        float v = acc[m][n][r];
        if (OUT_BF16)
          ((u16*)Cv)[(size_t)rg * N + cg] = f2bf(v);
        else
          ((float*)Cv)[(size_t)rg * N + cg] = v;
      }
}

// ---------------- exclusive cumsum over chunks (4-way split scan) ----------
__global__ __launch_bounds__(256) void cumsum_excl(const float* __restrict__ ck,
                                                   const float* __restrict__ cv,
                                                   float* __restrict__ cuk,
                                                   float* __restrict__ cuv) {
  __shared__ float qk[4][64], qv[4][64];
  int bh = blockIdx.x;                       // 64 blocks (b*16+h)
  int d = threadIdx.x & 63, q = threadIdx.x >> 6;
  size_t base = ((size_t)bh * 64) * 64 + d;
  float sk = 0.f, sv = 0.f;
  for (int c = q * 16; c < q * 16 + 16; c++) {
    sk += ck[base + (size_t)c * 64];
    sv += cv[base + (size_t)c * 64];
  }
  qk[q][d] = sk; qv[q][d] = sv;
  __syncthreads();
  float ak = 0.f, av = 0.f;
  for (int p = 0; p < q; p++) { ak += qk[p][d]; av += qv[p][d]; }
  for (int c = q * 16; c < q * 16 + 16; c++) {
    size_t i = base + (size_t)c * 64;
    cuk[i] = ak; cuv[i] = av;
    ak += ck[i]; av += cv[i];
  }
}

// ---------------- per-chunk attention + cross term ----------------
// LDS stride 88 (11x16B quads/row): staging-write quads (3r+2qt) cover all 8
// banks-quads; p_s writes 4-way (was 8). vt_s chunk-XOR swizzle: write col
// (r&7)|(((r>>3)^qt)<<3); read at [n*16+lr][kt*32+((g^n)<<3)] -- d'>>4==n is
// instr-constant so read pattern unchanged; write conflicts ~8->2-way.
__global__ __launch_bounds__(256) void attn_kernel(const u16* __restrict__ qkv,
                                                   const float* __restrict__ cuk,
                                                   const float* __restrict__ cuv,
                                                   u16* __restrict__ out) {
  int blk = blockIdx.x;
  int c = blk & 63, h = (blk >> 6) & 15, b = blk >> 10;
  int row0 = b * SEQ + c * 64;
  __shared__ u16 q_s[64][88];
  __shared__ u16 k_s[64][88];
  __shared__ u16 vt_s[64][88];   // V transposed + chunk-XOR swizzled
  __shared__ u16 p_s[64][88];
  __shared__ u16 ck_s[64];
  __shared__ float cv_s[64];
  int tid = threadIdx.x;
  {
    int r = tid >> 2, qt = tid & 3;
    const u16* rp = qkv + (size_t)(row0 + r) * QKVC + h * 64 + qt * 16;
    uint4 q0 = *(const uint4*)rp;          uint4 q1 = *(const uint4*)(rp + 8);
    uint4 k0 = *(const uint4*)(rp + 1024); uint4 k1 = *(const uint4*)(rp + 1032);
    uint4 v0 = *(const uint4*)(rp + 2048); uint4 v1 = *(const uint4*)(rp + 2056);
    *(uint4*)&q_s[r][qt * 16] = q0;     *(uint4*)&q_s[r][qt * 16 + 8] = q1;
    *(uint4*)&k_s[r][qt * 16] = k0;     *(uint4*)&k_s[r][qt * 16 + 8] = k1;
    const u16* vv0 = (const u16*)&v0;   const u16* vv1 = (const u16*)&v1;
    int vcol = (r & 7) | ((((r >> 3) ^ qt) & 7) << 3);
#pragma unroll
    for (int j = 0; j < 8; j++) vt_s[qt * 16 + j][vcol] = vv0[j];
#pragma unroll
    for (int j = 0; j < 8; j++) vt_s[qt * 16 + 8 + j][vcol] = vv1[j];
    if (tid < 64) {
      ck_s[tid] = f2bf(cuk[(size_t)blk * 64 + tid]);
      cv_s[tid] = cuv[(size_t)blk * 64 + tid];
    }
  }
  __syncthreads();

  int lane = tid & 63, w = tid >> 6;
  int lr = lane & 15, g = lane >> 4;
  f32x4 accS[4];
#pragma unroll
  for (int n = 0; n < 4; n++) accS[n] = (f32x4){0.f, 0.f, 0.f, 0.f};
  f32x4 accC = (f32x4){0.f, 0.f, 0.f, 0.f};
  short8 zf = (short8){0, 0, 0, 0, 0, 0, 0, 0};
#pragma unroll
  for (int kt = 0; kt < 2; kt++) {
    int lk = kt * 32 + g * 8;
    short8 af = *(const short8*)&q_s[w * 16 + lr][lk];
    short8 cf = (lr == 0) ? *(const short8*)&ck_s[lk] : zf;
    accC = __builtin_amdgcn_mfma_f32_16x16x32_bf16(af, cf, accC, 0, 0, 0);
#pragma unroll
    for (int n = 0; n < 4; n++) {
      short8 bf = *(const short8*)&k_s[n * 16 + lr][lk];
      accS[n] = __builtin_amdgcn_mfma_f32_16x16x32_bf16(af, bf, accS[n], 0, 0, 0);
    }
  }
  float crossv[4];
#pragma unroll
  for (int r4 = 0; r4 < 4; r4++) {
    int row = w * 16 + g * 4 + r4;
    float x[4];
    float mx = -3.4e38f;
#pragma unroll
    for (int n = 0; n < 4; n++) {
      int col = n * 16 + lr;
      x[n] = ((col & 63) > (row & 63)) ? -65000.0f : accS[n][r4] * SCALE;
      mx = fmaxf(mx, x[n]);
    }
    mx = fmaxf(mx, __shfl_xor(mx, 1));
    mx = fmaxf(mx, __shfl_xor(mx, 2));
    mx = fmaxf(mx, __shfl_xor(mx, 4));
    mx = fmaxf(mx, __shfl_xor(mx, 8));
    float p[4], sum = 0.f;
#pragma unroll
    for (int n = 0; n < 4; n++) { p[n] = __expf(x[n] - mx); sum += p[n]; }
    sum += __shfl_xor(sum, 1);
    sum += __shfl_xor(sum, 2);
    sum += __shfl_xor(sum, 4);
    sum += __shfl_xor(sum, 8);
    float inv = 1.0f / sum;
#pragma unroll
    for (int n = 0; n < 4; n++) p_s[row][n * 16 + lr] = f2bf(p[n] * inv);
    float sg = 1.0f / (1.0f + __expf(-accC[r4] * SCALE));
    crossv[r4] = __shfl(sg, (lane & 48));
  }
  __syncthreads();
  f32x4 accO[4];
#pragma unroll
  for (int n = 0; n < 4; n++) accO[n] = (f32x4){0.f, 0.f, 0.f, 0.f};
#pragma unroll
  for (int kt = 0; kt < 2; kt++) {
    int lk = kt * 32 + g * 8;
    short8 pf = *(const short8*)&p_s[w * 16 + lr][lk];
#pragma unroll
    for (int n = 0; n < 4; n++) {
      short8 vf = *(const short8*)&vt_s[n * 16 + lr][kt * 32 + ((g ^ n) << 3)];
      accO[n] = __builtin_amdgcn_mfma_f32_16x16x32_bf16(pf, vf, accO[n], 0, 0, 0);
    }
  }
#pragma unroll
  for (int n = 0; n < 4; n++)
#pragma unroll
    for (int r4 = 0; r4 < 4; r4++) {
      int row = w * 16 + g * 4 + r4;
      int col = n * 16 + lr;
      float v = accO[n][r4] + crossv[r4] * cv_s[col] * 0.5f;
      out[(size_t)(row0 + row) * DIMC + h * 64 + col] = f2bf(v);
    }
}

extern "C" void kernel_launch(void* const* d_in, const int* in_sizes, int n_in,
                              void* d_out, int out_size, void* d_ws, size_t ws_size,
                              hipStream_t stream) {
  const float* x = (const float*)d_in[0];
  const float* Wqkv = (const float*)d_in[1];
  const float* Wout = (const float*)d_in[2];
  char* ws = (char*)d_ws;
  size_t off = 0;
  auto alloc = [&](size_t b) {
    void* p = ws + off;
    off += (b + 255) & ~(size_t)255;
    return p;
  };
  u16* xb = (u16*)alloc((size_t)NROWS * DIMC * 2);        // 32MB, reused as attnb
  u16* wqt = (u16*)alloc((size_t)QKVC * DIMC * 2);        // 6MB
  u16* wot = (u16*)alloc((size_t)DIMC * DIMC * 2);        // 2MB
  u16* qkvb = (u16*)alloc((size_t)NROWS * QKVC * 2);      // 96MB
  float* chk = (float*)alloc((size_t)4096 * 64 * 4);
  float* chv = (float*)alloc((size_t)4096 * 64 * 4);
  float* cuk = (float*)alloc((size_t)4096 * 64 * 4);
  float* cuv = (float*)alloc((size_t)4096 * 64 * 4);
  u16* attnb = xb;

  cvt_kernel<<<16384, 256, 0, stream>>>(x, xb, NROWS * DIMC / 4);
  transpose_cvt<<<3072, 256, 0, stream>>>(Wqkv, wqt, DIMC, QKVC);
  transpose_cvt<<<1024, 256, 0, stream>>>(Wout, wot, DIMC, DIMC);
  gemm_bt<1, 1><<<768, 512, 0, stream>>>(xb, wqt, qkvb, chk, chv, NROWS, QKVC, DIMC);
  cumsum_excl<<<64, 256, 0, stream>>>(chk, chv, cuk, cuv);
  attn_kernel<<<4096, 256, 0, stream>>>(qkvb, cuk, cuv, attnb);
  gemm_bt<0, 0><<<256, 512, 0, stream>>>(attnb, wot, d_out, nullptr, nullptr,
                                         NROWS, DIMC, DIMC);
}

// Round 12
// 196.560 us; speedup vs baseline: 1.1318x; 1.0205x over previous
//
#include <hip/hip_runtime.h>
#include <stdint.h>

typedef __attribute__((ext_vector_type(4))) float f32x4;
typedef __attribute__((ext_vector_type(8))) short short8;
typedef unsigned short u16;

#define NH 16
#define HD 64
#define SEQ 4096
#define BATCH 4
#define NROWS (BATCH * SEQ)      // 16384
#define DIMC 1024
#define QKVC 3072
#define SCALE 0.125f

__device__ __forceinline__ u16 f2bf(float f) {
  union { float f; uint32_t u; } v; v.f = f;
  uint32_t u = v.u;
  uint32_t r = (u + 0x7fffu + ((u >> 16) & 1u)) >> 16;
  return (u16)r;
}
__device__ __forceinline__ float bf2f(u16 h) {
  union { uint32_t u; float f; } v; v.u = ((uint32_t)h) << 16;
  return v.f;
}

// ---------------- fp32 -> bf16 elementwise convert (vectorized) ----------------
__global__ __launch_bounds__(256) void cvt_kernel(const float* __restrict__ in,
                                                  u16* __restrict__ out, int n4) {
  int i = blockIdx.x * 256 + threadIdx.x;
  if (i >= n4) return;
  float4 v = ((const float4*)in)[i];
  ushort4 o;
  o.x = f2bf(v.x); o.y = f2bf(v.y); o.z = f2bf(v.z); o.w = f2bf(v.w);
  ((ushort4*)out)[i] = o;
}

// ---------------- fp32 [R][C] -> bf16 [C][R] transpose ----------------
__global__ __launch_bounds__(256) void transpose_cvt(const float* __restrict__ in,
                                                     u16* __restrict__ out, int R, int C) {
  __shared__ float t[32][33];
  int nbx = C >> 5;
  int bx = blockIdx.x % nbx, by = blockIdx.x / nbx;
  int r0 = by << 5, c0 = bx << 5;
  int tid = threadIdx.x;
#pragma unroll
  for (int i = 0; i < 4; i++) {
    int id = i * 256 + tid; int lr = id >> 5, lc = id & 31;
    t[lr][lc] = in[(size_t)(r0 + lr) * C + (c0 + lc)];
  }
  __syncthreads();
#pragma unroll
  for (int i = 0; i < 4; i++) {
    int id = i * 256 + tid; int lr = id >> 5, lc = id & 31;
    out[(size_t)(c0 + lr) * R + (r0 + lc)] = f2bf(t[lc][lr]);
  }
}

// ---------------- bf16 GEMM: C[M,N] = A[M,K] * Bt[N,K]^T ----------------
// Round-6/11 structure (best measured: ~105us QKV, MfmaUtil 42.8%, 0 bank
// conflicts, no spill). BM=BN=256, BK=64, 512 thr = 8 waves (2M x 4N),
// per-wave 128x64 (acc[8][4], 16x16x32 MFMA). LDS 128 KiB = 2 dbuf.
// One barrier per K-tile; reads grouped ahead of MFMA staircase; compiler
// inserts counted lgkm waits so tail reads drain under MFMA. FROZEN.
template <int OUT_BF16, int DO_SUMS>
__global__ __launch_bounds__(512, 2) void gemm_bt(const u16* __restrict__ A,
                                                  const u16* __restrict__ Bt,
                                                  void* __restrict__ Cv,
                                                  float* __restrict__ chk,
                                                  float* __restrict__ chv,
                                                  int M, int N, int K) {
  __shared__ __align__(16) u16 lds2[2][32768];   // per dbuf: A[0..16383], B[16384..32767]
  int nbx = N >> 8;
  int nwg = gridDim.x;
  int bid = blockIdx.x;
  int cpx = nwg >> 3;                       // grids are multiples of 8
  int swz = (bid & 7) * cpx + (bid >> 3);
  int bx = swz % nbx, by = swz / nbx;
  int tid = threadIdx.x, lane = tid & 63, wv = tid >> 6;
  int wr = wv >> 2, wc = wv & 3;            // wave grid 2 (M) x 4 (N)
  int lr = lane & 15, g = lane >> 4;
  int rx = lr & 7;
  int rsub = lane >> 3;                     // staging: row within 8-row unit
  int clog = (lane & 7) ^ rsub;             // staging: logical (global) chunk

  const u16* Ap = A + (size_t)(by * 256) * K;
  const u16* Bp = Bt + (size_t)(bx * 256) * K;

  f32x4 acc[8][4];
#pragma unroll
  for (int m = 0; m < 8; m++)
#pragma unroll
    for (int n = 0; n < 4; n++) acc[m][n] = (f32x4){0.f, 0.f, 0.f, 0.f};

  short8 a0[4][2], a1[4][2], b0[2][2], b1[2][2];

#define ISSUE_A(HALF, L, T) do {                                                \
    int ru_ = (HALF) * 128 + (L) * 64 + wv * 8;                                 \
    const u16* g_ = Ap + (size_t)(ru_ + rsub) * K + (T) * 64 + clog * 8;        \
    __builtin_amdgcn_global_load_lds(                                           \
        (const __attribute__((address_space(1))) uint32_t*)g_,                  \
        (__attribute__((address_space(3))) uint32_t*)&lds2[(T) & 1][ru_ * 64],  \
        16, 0, 0);                                                              \
  } while (0)

#define ISSUE_B(HALF, L, T) do {                                                \
    int ru_ = (HALF) * 128 + (L) * 64 + wv * 8;                                 \
    const u16* g_ = Bp + (size_t)(ru_ + rsub) * K + (T) * 64 + clog * 8;        \
    __builtin_amdgcn_global_load_lds(                                           \
        (const __attribute__((address_space(1))) uint32_t*)g_,                  \
        (__attribute__((address_space(3)))                                      \
             uint32_t*)&lds2[(T) & 1][16384 + ru_ * 64],                        \
        16, 0, 0);                                                              \
  } while (0)

#define LDA4(DST, MH, T) do {                                                   \
    _Pragma("unroll")                                                           \
    for (int m2 = 0; m2 < 4; m2++) {                                            \
      int row_ = wr * 128 + ((MH) * 4 + m2) * 16 + lr;                          \
      const u16* bp_ = &lds2[(T) & 1][row_ * 64];                               \
      _Pragma("unroll")                                                         \
      for (int s = 0; s < 2; s++)                                               \
        DST[m2][s] = *(const short8*)(bp_ + (((s * 4 + g) ^ rx) << 3));         \
    }                                                                           \
  } while (0)

#define LDB(DST, NHh, T) do {                                                   \
    _Pragma("unroll")                                                           \
    for (int n2 = 0; n2 < 2; n2++) {                                            \
      int row_ = wc * 64 + ((NHh) * 2 + n2) * 16 + lr;                          \
      const u16* bp_ = &lds2[(T) & 1][16384 + row_ * 64];                       \
      _Pragma("unroll")                                                         \
      for (int s = 0; s < 2; s++)                                               \
        DST[n2][s] = *(const short8*)(bp_ + (((s * 4 + g) ^ rx) << 3));         \
    }                                                                           \
  } while (0)

#define MFMA_Q(MH, NHh, AA, BB) do {                                            \
    _Pragma("unroll")                                                           \
    for (int s = 0; s < 2; s++)                                                 \
      _Pragma("unroll")                                                         \
      for (int m2 = 0; m2 < 4; m2++)                                            \
        _Pragma("unroll")                                                       \
        for (int n2 = 0; n2 < 2; n2++)                                          \
          acc[(MH) * 4 + m2][(NHh) * 2 + n2] =                                  \
              __builtin_amdgcn_mfma_f32_16x16x32_bf16(                          \
                  AA[m2][s], BB[n2][s], acc[(MH) * 4 + m2][(NHh) * 2 + n2],     \
                  0, 0, 0);                                                     \
  } while (0)

  int NT = K >> 6;
  // prologue: stage tile 0 into buf0, drain
  ISSUE_A(0, 0, 0); ISSUE_A(0, 1, 0); ISSUE_A(1, 0, 0); ISSUE_A(1, 1, 0);
  ISSUE_B(0, 0, 0); ISSUE_B(0, 1, 0); ISSUE_B(1, 0, 0); ISSUE_B(1, 1, 0);
  __syncthreads();

  for (int t = 0; t < NT; t++) {
    // group 1: frags for Q00
    LDA4(a0, 0, t);
    LDB(b0, 0, t);
    __builtin_amdgcn_sched_barrier(0);
    // stage A of tile t+1 (other buffer; prior readers retired at last barrier)
    if (t + 1 < NT) {
      ISSUE_A(0, 0, t + 1); ISSUE_A(0, 1, t + 1);
      ISSUE_A(1, 0, t + 1); ISSUE_A(1, 1, t + 1);
    }
    __builtin_amdgcn_sched_barrier(0);
    // group 2: remaining frags
    LDB(b1, 1, t);
    LDA4(a1, 1, t);
    __builtin_amdgcn_sched_barrier(0);
    // stage B of tile t+1
    if (t + 1 < NT) {
      ISSUE_B(0, 0, t + 1); ISSUE_B(0, 1, t + 1);
      ISSUE_B(1, 0, t + 1); ISSUE_B(1, 1, t + 1);
    }
    __builtin_amdgcn_sched_barrier(0);
    // MFMA staircase: compiler-counted lgkm waits
    __builtin_amdgcn_s_setprio(1);
    MFMA_Q(0, 0, a0, b0);
    __builtin_amdgcn_sched_barrier(0);
    MFMA_Q(0, 1, a0, b1);
    __builtin_amdgcn_sched_barrier(0);
    MFMA_Q(1, 1, a1, b1);
    __builtin_amdgcn_sched_barrier(0);
    MFMA_Q(1, 0, a1, b0);
    __builtin_amdgcn_s_setprio(0);
    __syncthreads();   // drains own vmcnt (stages) + lgkm; one barrier per tile
  }

#undef ISSUE_A
#undef ISSUE_B
#undef LDA4
#undef LDB
#undef MFMA_Q

  int rb = by * 256 + wr * 128, cb = bx * 256 + wc * 64;

  if (DO_SUMS && cb >= 1024) {
    // fused chunk means: wave owns chunks (wr*2+mh); sum fp32 acc over rows.
#pragma unroll
    for (int mh = 0; mh < 2; mh++)
#pragma unroll
      for (int n = 0; n < 4; n++) {
        float sum = 0.f;
#pragma unroll
        for (int m = mh * 4; m < mh * 4 + 4; m++)
#pragma unroll
          for (int r = 0; r < 4; r++) sum += acc[m][n][r];
        sum += __shfl_xor(sum, 16);
        sum += __shfl_xor(sum, 32);
        if (g == 0) {
          int grb = rb + mh * 64;
          int b = grb >> 12, c = (grb >> 6) & 63;
          int cg = cb + n * 16 + lr;
          int col = cg & 1023;
          int h = col >> 6, d = col & 63;
          float* dst = (cg < 2048) ? chk : chv;
          dst[(((size_t)(b * 16 + h)) * 64 + c) * 64 + d] = sum * 0.015625f;
        }
      }
  }

#pragma unroll
  for (int m = 0; m < 8; m++)
#pragma unroll
    for (int n = 0; n < 4; n++)
#pragma unroll
      for (int r = 0; r < 4; r++) {
        int rg = rb + m * 16 + g * 4 + r;
        int cg = cb + n * 16 + lr;
        float v = acc[m][n][r];
        if (OUT_BF16)
          ((u16*)Cv)[(size_t)rg * N + cg] = f2bf(v);
        else
          ((float*)Cv)[(size_t)rg * N + cg] = v;
      }
}

// ---------------- exclusive cumsum over chunks (4-way split scan) ----------
__global__ __launch_bounds__(256) void cumsum_excl(const float* __restrict__ ck,
                                                   const float* __restrict__ cv,
                                                   float* __restrict__ cuk,
                                                   float* __restrict__ cuv) {
  __shared__ float qk[4][64], qv[4][64];
  int bh = blockIdx.x;                       // 64 blocks (b*16+h)
  int d = threadIdx.x & 63, q = threadIdx.x >> 6;
  size_t base = ((size_t)bh * 64) * 64 + d;
  float sk = 0.f, sv = 0.f;
  for (int c = q * 16; c < q * 16 + 16; c++) {
    sk += ck[base + (size_t)c * 64];
    sv += cv[base + (size_t)c * 64];
  }
  qk[q][d] = sk; qv[q][d] = sv;
  __syncthreads();
  float ak = 0.f, av = 0.f;
  for (int p = 0; p < q; p++) { ak += qk[p][d]; av += qv[p][d]; }
  for (int c = q * 16; c < q * 16 + 16; c++) {
    size_t i = base + (size_t)c * 64;
    cuk[i] = ak; cuv[i] = av;
    ak += ck[i]; av += cv[i];
  }
}

// ---------------- per-chunk attention + cross term ----------------
// LDS shrunk 45->34 KB (4 blocks/CU, was 3): p_s overlays q_s. Safe without
// an extra barrier: warp w reads only q_s rows [16w,16w+16) in QK^T and later
// writes P to exactly those rows; per-wave DS ops retire in order, and
// cross-warp row ranges are disjoint. vt_s keeps the r11 chunk-XOR swizzle
// (write col (r&7)|(((r>>3)^qt)<<3); read col kt*32+((g^n)<<3)).
__global__ __launch_bounds__(256) void attn_kernel(const u16* __restrict__ qkv,
                                                   const float* __restrict__ cuk,
                                                   const float* __restrict__ cuv,
                                                   u16* __restrict__ out) {
  int blk = blockIdx.x;
  int c = blk & 63, h = (blk >> 6) & 15, b = blk >> 10;
  int row0 = b * SEQ + c * 64;
  __shared__ u16 qp_s[64][88];   // Q during QK^T, then P for PV
  __shared__ u16 k_s[64][88];
  __shared__ u16 vt_s[64][88];   // V transposed + chunk-XOR swizzled
  __shared__ u16 ck_s[64];
  __shared__ float cv_s[64];
  int tid = threadIdx.x;
  {
    // cross-term vectors first: longest dependency chain (used at the end)
    if (tid < 64) {
      ck_s[tid] = f2bf(cuk[(size_t)blk * 64 + tid]);
      cv_s[tid] = cuv[(size_t)blk * 64 + tid];
    }
    int r = tid >> 2, qt = tid & 3;
    const u16* rp = qkv + (size_t)(row0 + r) * QKVC + h * 64 + qt * 16;
    uint4 q0 = *(const uint4*)rp;          uint4 q1 = *(const uint4*)(rp + 8);
    uint4 k0 = *(const uint4*)(rp + 1024); uint4 k1 = *(const uint4*)(rp + 1032);
    uint4 v0 = *(const uint4*)(rp + 2048); uint4 v1 = *(const uint4*)(rp + 2056);
    *(uint4*)&qp_s[r][qt * 16] = q0;    *(uint4*)&qp_s[r][qt * 16 + 8] = q1;
    *(uint4*)&k_s[r][qt * 16] = k0;     *(uint4*)&k_s[r][qt * 16 + 8] = k1;
    const u16* vv0 = (const u16*)&v0;   const u16* vv1 = (const u16*)&v1;
    int vcol = (r & 7) | ((((r >> 3) ^ qt) & 7) << 3);
#pragma unroll
    for (int j = 0; j < 8; j++) vt_s[qt * 16 + j][vcol] = vv0[j];
#pragma unroll
    for (int j = 0; j < 8; j++) vt_s[qt * 16 + 8 + j][vcol] = vv1[j];
  }
  __syncthreads();

  int lane = tid & 63, w = tid >> 6;
  int lr = lane & 15, g = lane >> 4;
  f32x4 accS[4];
#pragma unroll
  for (int n = 0; n < 4; n++) accS[n] = (f32x4){0.f, 0.f, 0.f, 0.f};
  f32x4 accC = (f32x4){0.f, 0.f, 0.f, 0.f};
  short8 zf = (short8){0, 0, 0, 0, 0, 0, 0, 0};
#pragma unroll
  for (int kt = 0; kt < 2; kt++) {
    int lk = kt * 32 + g * 8;
    short8 af = *(const short8*)&qp_s[w * 16 + lr][lk];
    short8 cf = (lr == 0) ? *(const short8*)&ck_s[lk] : zf;
    accC = __builtin_amdgcn_mfma_f32_16x16x32_bf16(af, cf, accC, 0, 0, 0);
#pragma unroll
    for (int n = 0; n < 4; n++) {
      short8 bf = *(const short8*)&k_s[n * 16 + lr][lk];
      accS[n] = __builtin_amdgcn_mfma_f32_16x16x32_bf16(af, bf, accS[n], 0, 0, 0);
    }
  }
  float crossv[4];
#pragma unroll
  for (int r4 = 0; r4 < 4; r4++) {
    int row = w * 16 + g * 4 + r4;
    float x[4];
    float mx = -3.4e38f;
#pragma unroll
    for (int n = 0; n < 4; n++) {
      int col = n * 16 + lr;
      x[n] = ((col & 63) > (row & 63)) ? -65000.0f : accS[n][r4] * SCALE;
      mx = fmaxf(mx, x[n]);
    }
    mx = fmaxf(mx, __shfl_xor(mx, 1));
    mx = fmaxf(mx, __shfl_xor(mx, 2));
    mx = fmaxf(mx, __shfl_xor(mx, 4));
    mx = fmaxf(mx, __shfl_xor(mx, 8));
    float p[4], sum = 0.f;
#pragma unroll
    for (int n = 0; n < 4; n++) { p[n] = __expf(x[n] - mx); sum += p[n]; }
    sum += __shfl_xor(sum, 1);
    sum += __shfl_xor(sum, 2);
    sum += __shfl_xor(sum, 4);
    sum += __shfl_xor(sum, 8);
    float inv = 1.0f / sum;
    // write P into qp_s (own warp's rows; Q reads above already retired in-order)
#pragma unroll
    for (int n = 0; n < 4; n++) qp_s[row][n * 16 + lr] = f2bf(p[n] * inv);
    float sg = 1.0f / (1.0f + __expf(-accC[r4] * SCALE));
    crossv[r4] = __shfl(sg, (lane & 48));
  }
  __syncthreads();
  f32x4 accO[4];
#pragma unroll
  for (int n = 0; n < 4; n++) accO[n] = (f32x4){0.f, 0.f, 0.f, 0.f};
#pragma unroll
  for (int kt = 0; kt < 2; kt++) {
    int lk = kt * 32 + g * 8;
    short8 pf = *(const short8*)&qp_s[w * 16 + lr][lk];
#pragma unroll
    for (int n = 0; n < 4; n++) {
      short8 vf = *(const short8*)&vt_s[n * 16 + lr][kt * 32 + ((g ^ n) << 3)];
      accO[n] = __builtin_amdgcn_mfma_f32_16x16x32_bf16(pf, vf, accO[n], 0, 0, 0);
    }
  }
#pragma unroll
  for (int n = 0; n < 4; n++)
#pragma unroll
    for (int r4 = 0; r4 < 4; r4++) {
      int row = w * 16 + g * 4 + r4;
      int col = n * 16 + lr;
      float v = accO[n][r4] + crossv[r4] * cv_s[col] * 0.5f;
      out[(size_t)(row0 + row) * DIMC + h * 64 + col] = f2bf(v);
    }
}

extern "C" void kernel_launch(void* const* d_in, const int* in_sizes, int n_in,
                              void* d_out, int out_size, void* d_ws, size_t ws_size,
                              hipStream_t stream) {
  const float* x = (const float*)d_in[0];
  const float* Wqkv = (const float*)d_in[1];
  const float* Wout = (const float*)d_in[2];
  char* ws = (char*)d_ws;
  size_t off = 0;
  auto alloc = [&](size_t b) {
    void* p = ws + off;
    off += (b + 255) & ~(size_t)255;
    return p;
  };
  u16* xb = (u16*)alloc((size_t)NROWS * DIMC * 2);        // 32MB, reused as attnb
  u16* wqt = (u16*)alloc((size_t)QKVC * DIMC * 2);        // 6MB
  u16* wot = (u16*)alloc((size_t)DIMC * DIMC * 2);        // 2MB
  u16* qkvb = (u16*)alloc((size_t)NROWS * QKVC * 2);      // 96MB
  float* chk = (float*)alloc((size_t)4096 * 64 * 4);
  float* chv = (float*)alloc((size_t)4096 * 64 * 4);
  float* cuk = (float*)alloc((size_t)4096 * 64 * 4);
  float* cuv = (float*)alloc((size_t)4096 * 64 * 4);
  u16* attnb = xb;

  cvt_kernel<<<16384, 256, 0, stream>>>(x, xb, NROWS * DIMC / 4);
  transpose_cvt<<<3072, 256, 0, stream>>>(Wqkv, wqt, DIMC, QKVC);
  transpose_cvt<<<1024, 256, 0, stream>>>(Wout, wot, DIMC, DIMC);
  gemm_bt<1, 1><<<768, 512, 0, stream>>>(xb, wqt, qkvb, chk, chv, NROWS, QKVC, DIMC);
  cumsum_excl<<<64, 256, 0, stream>>>(chk, chv, cuk, cuv);
  attn_kernel<<<4096, 256, 0, stream>>>(qkvb, cuk, cuv, attnb);
  gemm_bt<0, 0><<<256, 512, 0, stream>>>(attnb, wot, d_out, nullptr, nullptr,
                                         NROWS, DIMC, DIMC);
}